// Round 19
// baseline (1172.818 us; speedup 1.0000x reference)
//
#include <hip/hip_runtime.h>

// HybridGeometryFeatures via spatial grid (EXACT selection).
// r18 structure with ONE fix: the group-min termination previously did
// MIN64(m, shfl_xor_u64(m, k)) — the ternary macro re-evaluates the SHUFFLE
// in a divergent branch (reads from exec-masked lanes -> garbage -> premature
// break). Fix: hoist each shuffle into a register before the min (the r4-proven
// pattern). Dealing, enumeration, bound, halver/merge math all r17/r18-audited.

#define NPTS 12288
#define NBATCH 2
#define NQ (NPTS * NBATCH)
#define KNN 16
#define GD 32
#define GD3 (GD * GD * GD)
#define OFFST (GD3 + 1)
#define CLO (-6.0f)
#define CW 0.375f
#define LPQ 8

typedef unsigned long long u64;
typedef unsigned int u32;

#define MIN64(a, b) ((a) < (b) ? (a) : (b))
#define SWAP64(a, b) { u64 _lo = (a) < (b) ? (a) : (b); u64 _hi = (a) < (b) ? (b) : (a); a = _lo; b = _hi; }

__device__ __forceinline__ int cellc(float v) {
  int c = (int)((v - CLO) * (1.0f / CW));
  return c < 0 ? 0 : (c > GD - 1 ? GD - 1 : c);
}

__device__ __forceinline__ u64 shfl_xor_u64(u64 v, int mask) {
  u32 lo = (u32)v, hi = (u32)(v >> 32);
  lo = (u32)__shfl_xor((int)lo, mask);
  hi = (u32)__shfl_xor((int)hi, mask);
  return ((u64)hi << 32) | lo;
}

__global__ __launch_bounds__(256) void zero_kernel(u32* __restrict__ cnt) {
  int i = blockIdx.x * 256 + threadIdx.x;
  if (i < 2 * GD3) cnt[i] = 0;
}

__global__ __launch_bounds__(256) void pack_kernel(const float* __restrict__ xyz,
                                                   float4* __restrict__ pts4,
                                                   u32* __restrict__ cellid,
                                                   u32* __restrict__ cnt) {
  int i = blockIdx.x * 256 + threadIdx.x;
  if (i < NQ) {
    float x = xyz[3 * i + 0], y = xyz[3 * i + 1], z = xyz[3 * i + 2];
    pts4[i] = make_float4(x, y, z, 0.0f);
    u32 cell = (u32)((cellc(z) * GD + cellc(y)) * GD + cellc(x));
    cellid[i] = cell;
    int b = i / NPTS;
    atomicAdd(&cnt[b * GD3 + cell], 1u);
  }
}

// Exclusive scan of 32768 counts per batch (blockIdx = batch).
__global__ __launch_bounds__(1024) void scan_kernel(const u32* __restrict__ cnt,
                                                    u32* __restrict__ off,
                                                    u32* __restrict__ cur) {
  __shared__ u32 part[1024];
  int b = blockIdx.x;
  int tid = threadIdx.x;
  const u32* cb = cnt + b * GD3;
  u32* ob = off + b * OFFST;
  u32* ub = cur + b * GD3;
  u32 tmp[32];
  u32 s = 0;
#pragma unroll
  for (int i = 0; i < 32; ++i) {
    u32 c = cb[tid * 32 + i];
    tmp[i] = s;
    s += c;
  }
  part[tid] = s;
  __syncthreads();
  for (int o = 1; o < 1024; o <<= 1) {
    u32 v = (tid >= o) ? part[tid - o] : 0u;
    __syncthreads();
    part[tid] += v;
    __syncthreads();
  }
  u32 prefix = (tid == 0) ? 0u : part[tid - 1];
#pragma unroll
  for (int i = 0; i < 32; ++i) {
    u32 v = prefix + tmp[i];
    ob[tid * 32 + i] = v;
    ub[tid * 32 + i] = v;
  }
  if (tid == 1023) ob[GD3] = part[1023];
}

__global__ __launch_bounds__(256) void scatter_kernel(const float4* __restrict__ pts4,
                                                      const u32* __restrict__ cellid,
                                                      u32* __restrict__ cur,
                                                      float4* __restrict__ spts) {
  int i = blockIdx.x * 256 + threadIdx.x;
  if (i < NQ) {
    int b = i / NPTS;
    u32 cell = cellid[i];
    u32 pos = atomicAdd(&cur[b * GD3 + cell], 1u);
    float4 p = pts4[i];
    p.w = (float)(i - b * NPTS); // original local index as exact float value
    spts[b * NPTS + pos] = p;
  }
}

// 8 LANES PER QUERY. Shell expansion with round-robin range dealing; per-lane
// exact u64 top-16 (r17-proven network); FIXED group-min termination; 3-stage
// shfl_xor bitonic merge; features on lane g==0.
__global__ __launch_bounds__(64) void query_kernel(const float4* __restrict__ pts4,
                                                   const float4* __restrict__ spts,
                                                   const u32* __restrict__ off,
                                                   const float* __restrict__ normals,
                                                   float* __restrict__ out) {
  int lane = threadIdx.x;
  int g = lane & (LPQ - 1);
  int t = blockIdx.x * (64 / LPQ) + (lane >> 3); // 8 queries per wave
  int b = t / NPTS;
  int j = t - b * NPTS;
  int bbase = b * NPTS;
  const float4* sp = spts + bbase;
  const u32* ob = off + b * OFFST;

  float4 Q4 = sp[j];
  float Qx = Q4.x, Qy = Q4.y, Qz = Q4.z;
  u32 qi = (u32)(int)Q4.w;
  int cqx = cellc(Qx), cqy = cellc(Qy), cqz = cellc(Qz);

  u64 run[KNN];
#pragma unroll
  for (int i = 0; i < KNN; ++i) run[i] = ~0ULL;

  auto proc8 = [&](int s, int e) {
    for (int j0 = s; j0 < e; j0 += 8) {
      u64 s0, s1, s2, s3, s4, s5, s6, s7;
#define MK(sv, M) { int jp = j0 + (M); float4 c = sp[jp < e ? jp : e - 1]; \
      float dx = Qx - c.x, dy = Qy - c.y, dz = Qz - c.z; \
      float d2 = fmaf(dz, dz, fmaf(dy, dy, dx * dx)); \
      u32 ci = (u32)(int)c.w; \
      sv = ((u64)__float_as_uint(d2) << 32) | ci; \
      if (jp >= e || ci == qi) sv = ~0ULL; }
      MK(s0, 0) MK(s1, 1) MK(s2, 2) MK(s3, 3) MK(s4, 4) MK(s5, 5) MK(s6, 6) MK(s7, 7)
#undef MK
      u64 qmin = MIN64(MIN64(MIN64(s0, s1), MIN64(s2, s3)),
                       MIN64(MIN64(s4, s5), MIN64(s6, s7)));
      if (qmin < run[15]) {
        // Batcher sort-8 ascending (r17-proven)
        SWAP64(s0, s1) SWAP64(s2, s3) SWAP64(s4, s5) SWAP64(s6, s7)
        SWAP64(s0, s2) SWAP64(s1, s3) SWAP64(s4, s6) SWAP64(s5, s7)
        SWAP64(s1, s2) SWAP64(s5, s6)
        SWAP64(s0, s4) SWAP64(s1, s5) SWAP64(s2, s6) SWAP64(s3, s7)
        SWAP64(s2, s4) SWAP64(s3, s5)
        SWAP64(s1, s2) SWAP64(s3, s4) SWAP64(s5, s6)
        // halver + bitonic-merge-16 (r17-proven)
        run[8]  = MIN64(run[8],  s7);
        run[9]  = MIN64(run[9],  s6);
        run[10] = MIN64(run[10], s5);
        run[11] = MIN64(run[11], s4);
        run[12] = MIN64(run[12], s3);
        run[13] = MIN64(run[13], s2);
        run[14] = MIN64(run[14], s1);
        run[15] = MIN64(run[15], s0);
#pragma unroll
        for (int jj = 8; jj >= 1; jj >>= 1) {
#pragma unroll
          for (int ii = 0; ii < KNN; ++ii) {
            if ((ii & jj) == 0) { SWAP64(run[ii], run[ii | jj]) }
          }
        }
      }
    }
  };

  int rr = 0; // deterministic range counter, identical across the 8 group lanes
  for (int k = 0; k < GD; ++k) {
    for (int dz = -k; dz <= k; ++dz) {
      int cz = cqz + dz;
      if (cz < 0 || cz >= GD) continue;
      bool zface = (dz == -k) || (dz == k);
      for (int dy = -k; dy <= k; ++dy) {
        int cy = cqy + dy;
        if (cy < 0 || cy >= GD) continue;
        int rowbase = (cz * GD + cy) * GD;
        if (zface || dy == -k || dy == k) {
          int x0 = cqx - k; if (x0 < 0) x0 = 0;
          int x1 = cqx + k; if (x1 > GD - 1) x1 = GD - 1;
          if ((rr++ & (LPQ - 1)) == g) {
            int s = (int)ob[rowbase + x0], e = (int)ob[rowbase + x1 + 1];
            if (s < e) proc8(s, e);
          }
        } else {
          int xa = cqx - k;
          if (xa >= 0) {
            if ((rr++ & (LPQ - 1)) == g) {
              int s = (int)ob[rowbase + xa], e = (int)ob[rowbase + xa + 1];
              if (s < e) proc8(s, e);
            }
          }
          int xb = cqx + k;
          if (xb < GD) {
            if ((rr++ & (LPQ - 1)) == g) {
              int s = (int)ob[rowbase + xb], e = (int)ob[rowbase + xb + 1];
              if (s < e) proc8(s, e);
            }
          }
        }
      }
    }
    // group termination: union d16 <= min over the 8 lanes of run[15].
    // FIX: hoist each shuffle into a register BEFORE the compare (the MIN64
    // macro re-evaluated the shuffle inside a divergent ternary -> UB).
    u64 m = run[15];
    {
      u64 o1 = shfl_xor_u64(m, 1);
      m = o1 < m ? o1 : m;
      u64 o2 = shfl_xor_u64(m, 2);
      m = o2 < m ? o2 : m;
      u64 o4 = shfl_xor_u64(m, 4);
      m = o4 < m ? o4 : m;
    }
    float d16 = __uint_as_float((u32)(m >> 32)); // NaN while no lane full -> no stop
    float kw = (float)k * CW;
    if (d16 < kw * kw * 0.9999f) break;
  }

  // 3-stage shuffle merge (shuffles hoisted into oth[] -> safe): after each
  // stage all lanes in the widening group hold the same sorted lowest-16.
#pragma unroll
  for (int st = 1; st <= 4; st <<= 1) {
    u64 oth[KNN];
#pragma unroll
    for (int i = 0; i < KNN; ++i) oth[i] = shfl_xor_u64(run[i], st);
#pragma unroll
    for (int i = 0; i < KNN; ++i) run[i] = MIN64(run[i], oth[KNN - 1 - i]);
#pragma unroll
    for (int jj = 8; jj >= 1; jj >>= 1) {
#pragma unroll
      for (int ii = 0; ii < KNN; ++ii) {
        if ((ii & jj) == 0) { SWAP64(run[ii], run[ii | jj]) }
      }
    }
  }

  if (g != 0) return;

  // ---- features (r17-proven epilogue) ----
  float nx[KNN], ny[KNN], nz[KNN];
  float sx = 0.f, sy = 0.f, sz = 0.f;
#pragma unroll
  for (int i = 0; i < KNN; ++i) {
    int ni = (int)(u32)run[i];
    float4 c4 = pts4[bbase + ni];
    nx[i] = c4.x; ny[i] = c4.y; nz[i] = c4.z;
    sx += c4.x; sy += c4.y; sz += c4.z;
  }
  const float invK = 1.0f / 16.0f;
  float cx = sx * invK, cy = sy * invK, cz = sz * invK;

  float c00 = 0.f, c01 = 0.f, c02 = 0.f, c11 = 0.f, c12 = 0.f, c22 = 0.f;
#pragma unroll
  for (int i = 0; i < KNN; ++i) {
    float dx = nx[i] - cx, dy = ny[i] - cy, dz = nz[i] - cz;
    c00 += dx * dx; c01 += dx * dy; c02 += dx * dz;
    c11 += dy * dy; c12 += dy * dz; c22 += dz * dz;
  }
  const float inv15 = 1.0f / 15.0f;
  c00 *= inv15; c01 *= inv15; c02 *= inv15;
  c11 *= inv15; c12 *= inv15; c22 *= inv15;

  double a00 = c00, a01 = c01, a02 = c02, a11 = c11, a12 = c12, a22 = c22;
  double tr = a00 + a11 + a22;
  double qm = tr * (1.0 / 3.0);
  double p1 = a01 * a01 + a02 * a02 + a12 * a12;
  double b00 = a00 - qm, b11 = a11 - qm, b22 = a22 - qm;
  double p2 = b00 * b00 + b11 * b11 + b22 * b22 + 2.0 * p1;
  double lmin = qm;
  if (p2 > 0.0) {
    double p = sqrt(p2 * (1.0 / 6.0));
    double ip = 1.0 / p;
    double q00 = b00 * ip, q01 = a01 * ip, q02 = a02 * ip;
    double q11 = b11 * ip, q12 = a12 * ip, q22 = b22 * ip;
    double det = q00 * (q11 * q22 - q12 * q12) - q01 * (q01 * q22 - q12 * q02) +
                 q02 * (q01 * q12 - q11 * q02);
    double r = 0.5 * det;
    r = r < -1.0 ? -1.0 : (r > 1.0 ? 1.0 : r);
    double phi = acos(r) * (1.0 / 3.0);
    lmin = qm + 2.0 * p * cos(phi + 2.0943951023931953);
  }

  double m00 = a00 - lmin, m11 = a11 - lmin, m22 = a22 - lmin;
  double v0x = a01 * a12 - a02 * m11;
  double v0y = a02 * a01 - m00 * a12;
  double v0z = m00 * m11 - a01 * a01;
  double v1x = a01 * m22 - a02 * a12;
  double v1y = a02 * a02 - m00 * m22;
  double v1z = m00 * a12 - a01 * a02;
  double v2x = m11 * m22 - a12 * a12;
  double v2y = a12 * a02 - a01 * m22;
  double v2z = a01 * a12 - m11 * a02;
  double n0 = v0x * v0x + v0y * v0y + v0z * v0z;
  double n1 = v1x * v1x + v1y * v1y + v1z * v1z;
  double n2 = v2x * v2x + v2y * v2y + v2z * v2z;
  double vx, vy, vz, nn;
  if (n0 >= n1 && n0 >= n2) { vx = v0x; vy = v0y; vz = v0z; nn = n0; }
  else if (n1 >= n2)        { vx = v1x; vy = v1y; vz = v1z; nn = n1; }
  else                      { vx = v2x; vy = v2y; vz = v2z; nn = n2; }
  if (nn < 1e-60) { vx = 0.0; vy = 0.0; vz = 1.0; nn = 1.0; }
  double inn = 1.0 / sqrt(nn);
  float vxf = (float)(vx * inn), vyf = (float)(vy * inn), vzf = (float)(vz * inn);

  float s = 0.f;
#pragma unroll
  for (int i = 0; i < KNN; ++i) {
    s += fabsf((nx[i] - cx) * vxf + (ny[i] - cy) * vyf + (nz[i] - cz) * vzf);
  }

  int to = bbase + (int)qi;
  float nrx = normals[3 * (size_t)to + 0];
  float nry = normals[3 * (size_t)to + 1];
  float nrz = normals[3 * (size_t)to + 2];
  float dot = vxf * nrx + vyf * nry + vzf * nrz;
  float cons = fabsf(dot);
  float trf = c00 + c11 + c22;
  float curv = (float)lmin / fmaxf(trf, 1e-8f);
  float* o = out + (size_t)to * 6;
  o[0] = cons;
  o[1] = nrx;
  o[2] = nry;
  o[3] = nrz;
  o[4] = curv;
  o[5] = s * invK;
}

extern "C" void kernel_launch(void* const* d_in, const int* in_sizes, int n_in,
                              void* d_out, int out_size, void* d_ws, size_t ws_size,
                              hipStream_t stream) {
  const float* xyz = (const float*)d_in[0];
  const float* normals = (const float*)d_in[1];
  float* out = (float*)d_out;

  float4* pts4 = (float4*)d_ws;            // NQ
  float4* spts = pts4 + NQ;                // NQ (cell-sorted, w=(float)idx)
  u32* cnt = (u32*)(spts + NQ);            // 2*GD3
  u32* cur = cnt + 2 * GD3;                // 2*GD3
  u32* off = cur + 2 * GD3;                // 2*OFFST
  u32* cellid = off + 2 * OFFST;           // NQ

  zero_kernel<<<(2 * GD3) / 256, 256, 0, stream>>>(cnt);
  pack_kernel<<<NQ / 256, 256, 0, stream>>>(xyz, pts4, cellid, cnt);
  scan_kernel<<<2, 1024, 0, stream>>>(cnt, off, cur);
  scatter_kernel<<<NQ / 256, 256, 0, stream>>>(pts4, cellid, cur, spts);
  query_kernel<<<NQ / (64 / LPQ), 64, 0, stream>>>(pts4, spts, off, normals, out);
}

// Round 20
// 1104.410 us; speedup vs baseline: 1.0619x; 1.0619x over previous
//
#include <hip/hip_runtime.h>

// HybridGeometryFeatures via spatial grid (EXACT selection).
// r19 (passing, absmax 0.0039) + ONE fix: group-shared pruning threshold.
// r19's 9x busy-work amplification: each lane's local run[15] (~128th-best
// globally) made the insert-guard useless. Now guard with
// thr = min(run[15], groupthr) where groupthr = per-shell group-min of run[15]
// (>= final merged 16th at all times -> skipping keys >= groupthr is exact).

#define NPTS 12288
#define NBATCH 2
#define NQ (NPTS * NBATCH)
#define KNN 16
#define GD 32
#define GD3 (GD * GD * GD)
#define OFFST (GD3 + 1)
#define CLO (-6.0f)
#define CW 0.375f
#define LPQ 8

typedef unsigned long long u64;
typedef unsigned int u32;

#define MIN64(a, b) ((a) < (b) ? (a) : (b))
#define SWAP64(a, b) { u64 _lo = (a) < (b) ? (a) : (b); u64 _hi = (a) < (b) ? (b) : (a); a = _lo; b = _hi; }

__device__ __forceinline__ int cellc(float v) {
  int c = (int)((v - CLO) * (1.0f / CW));
  return c < 0 ? 0 : (c > GD - 1 ? GD - 1 : c);
}

__device__ __forceinline__ u64 shfl_xor_u64(u64 v, int mask) {
  u32 lo = (u32)v, hi = (u32)(v >> 32);
  lo = (u32)__shfl_xor((int)lo, mask);
  hi = (u32)__shfl_xor((int)hi, mask);
  return ((u64)hi << 32) | lo;
}

__global__ __launch_bounds__(256) void zero_kernel(u32* __restrict__ cnt) {
  int i = blockIdx.x * 256 + threadIdx.x;
  if (i < 2 * GD3) cnt[i] = 0;
}

__global__ __launch_bounds__(256) void pack_kernel(const float* __restrict__ xyz,
                                                   float4* __restrict__ pts4,
                                                   u32* __restrict__ cellid,
                                                   u32* __restrict__ cnt) {
  int i = blockIdx.x * 256 + threadIdx.x;
  if (i < NQ) {
    float x = xyz[3 * i + 0], y = xyz[3 * i + 1], z = xyz[3 * i + 2];
    pts4[i] = make_float4(x, y, z, 0.0f);
    u32 cell = (u32)((cellc(z) * GD + cellc(y)) * GD + cellc(x));
    cellid[i] = cell;
    int b = i / NPTS;
    atomicAdd(&cnt[b * GD3 + cell], 1u);
  }
}

// Exclusive scan of 32768 counts per batch (blockIdx = batch).
__global__ __launch_bounds__(1024) void scan_kernel(const u32* __restrict__ cnt,
                                                    u32* __restrict__ off,
                                                    u32* __restrict__ cur) {
  __shared__ u32 part[1024];
  int b = blockIdx.x;
  int tid = threadIdx.x;
  const u32* cb = cnt + b * GD3;
  u32* ob = off + b * OFFST;
  u32* ub = cur + b * GD3;
  u32 tmp[32];
  u32 s = 0;
#pragma unroll
  for (int i = 0; i < 32; ++i) {
    u32 c = cb[tid * 32 + i];
    tmp[i] = s;
    s += c;
  }
  part[tid] = s;
  __syncthreads();
  for (int o = 1; o < 1024; o <<= 1) {
    u32 v = (tid >= o) ? part[tid - o] : 0u;
    __syncthreads();
    part[tid] += v;
    __syncthreads();
  }
  u32 prefix = (tid == 0) ? 0u : part[tid - 1];
#pragma unroll
  for (int i = 0; i < 32; ++i) {
    u32 v = prefix + tmp[i];
    ob[tid * 32 + i] = v;
    ub[tid * 32 + i] = v;
  }
  if (tid == 1023) ob[GD3] = part[1023];
}

__global__ __launch_bounds__(256) void scatter_kernel(const float4* __restrict__ pts4,
                                                      const u32* __restrict__ cellid,
                                                      u32* __restrict__ cur,
                                                      float4* __restrict__ spts) {
  int i = blockIdx.x * 256 + threadIdx.x;
  if (i < NQ) {
    int b = i / NPTS;
    u32 cell = cellid[i];
    u32 pos = atomicAdd(&cur[b * GD3 + cell], 1u);
    float4 p = pts4[i];
    p.w = (float)(i - b * NPTS); // original local index as exact float value
    spts[b * NPTS + pos] = p;
  }
}

// 8 LANES PER QUERY. Shell expansion with round-robin range dealing; per-lane
// exact u64 top-16; group-min termination AND group-shared pruning threshold;
// 3-stage shfl_xor bitonic merge; features on lane g==0.
__global__ __launch_bounds__(64) void query_kernel(const float4* __restrict__ pts4,
                                                   const float4* __restrict__ spts,
                                                   const u32* __restrict__ off,
                                                   const float* __restrict__ normals,
                                                   float* __restrict__ out) {
  int lane = threadIdx.x;
  int g = lane & (LPQ - 1);
  int t = blockIdx.x * (64 / LPQ) + (lane >> 3); // 8 queries per wave
  int b = t / NPTS;
  int j = t - b * NPTS;
  int bbase = b * NPTS;
  const float4* sp = spts + bbase;
  const u32* ob = off + b * OFFST;

  float4 Q4 = sp[j];
  float Qx = Q4.x, Qy = Q4.y, Qz = Q4.z;
  u32 qi = (u32)(int)Q4.w;
  int cqx = cellc(Qx), cqy = cellc(Qy), cqz = cellc(Qz);

  u64 run[KNN];
#pragma unroll
  for (int i = 0; i < KNN; ++i) run[i] = ~0ULL;
  u64 groupthr = ~0ULL; // group-min of run[15] from previous shells (exact prune)

  auto proc8 = [&](int s, int e) {
    for (int j0 = s; j0 < e; j0 += 8) {
      u64 s0, s1, s2, s3, s4, s5, s6, s7;
#define MK(sv, M) { int jp = j0 + (M); float4 c = sp[jp < e ? jp : e - 1]; \
      float dx = Qx - c.x, dy = Qy - c.y, dz = Qz - c.z; \
      float d2 = fmaf(dz, dz, fmaf(dy, dy, dx * dx)); \
      u32 ci = (u32)(int)c.w; \
      sv = ((u64)__float_as_uint(d2) << 32) | ci; \
      if (jp >= e || ci == qi) sv = ~0ULL; }
      MK(s0, 0) MK(s1, 1) MK(s2, 2) MK(s3, 3) MK(s4, 4) MK(s5, 5) MK(s6, 6) MK(s7, 7)
#undef MK
      u64 qmin = MIN64(MIN64(MIN64(s0, s1), MIN64(s2, s3)),
                       MIN64(MIN64(s4, s5), MIN64(s6, s7)));
      u64 thr = MIN64(run[15], groupthr);
      if (qmin < thr) {
        // Batcher sort-8 ascending (r17-proven)
        SWAP64(s0, s1) SWAP64(s2, s3) SWAP64(s4, s5) SWAP64(s6, s7)
        SWAP64(s0, s2) SWAP64(s1, s3) SWAP64(s4, s6) SWAP64(s5, s7)
        SWAP64(s1, s2) SWAP64(s5, s6)
        SWAP64(s0, s4) SWAP64(s1, s5) SWAP64(s2, s6) SWAP64(s3, s7)
        SWAP64(s2, s4) SWAP64(s3, s5)
        SWAP64(s1, s2) SWAP64(s3, s4) SWAP64(s5, s6)
        // halver + bitonic-merge-16 (r17-proven)
        run[8]  = MIN64(run[8],  s7);
        run[9]  = MIN64(run[9],  s6);
        run[10] = MIN64(run[10], s5);
        run[11] = MIN64(run[11], s4);
        run[12] = MIN64(run[12], s3);
        run[13] = MIN64(run[13], s2);
        run[14] = MIN64(run[14], s1);
        run[15] = MIN64(run[15], s0);
#pragma unroll
        for (int jj = 8; jj >= 1; jj >>= 1) {
#pragma unroll
          for (int ii = 0; ii < KNN; ++ii) {
            if ((ii & jj) == 0) { SWAP64(run[ii], run[ii | jj]) }
          }
        }
      }
    }
  };

  int rr = 0; // deterministic range counter, identical across the 8 group lanes
  for (int k = 0; k < GD; ++k) {
    for (int dz = -k; dz <= k; ++dz) {
      int cz = cqz + dz;
      if (cz < 0 || cz >= GD) continue;
      bool zface = (dz == -k) || (dz == k);
      for (int dy = -k; dy <= k; ++dy) {
        int cy = cqy + dy;
        if (cy < 0 || cy >= GD) continue;
        int rowbase = (cz * GD + cy) * GD;
        if (zface || dy == -k || dy == k) {
          int x0 = cqx - k; if (x0 < 0) x0 = 0;
          int x1 = cqx + k; if (x1 > GD - 1) x1 = GD - 1;
          if ((rr++ & (LPQ - 1)) == g) {
            int s = (int)ob[rowbase + x0], e = (int)ob[rowbase + x1 + 1];
            if (s < e) proc8(s, e);
          }
        } else {
          int xa = cqx - k;
          if (xa >= 0) {
            if ((rr++ & (LPQ - 1)) == g) {
              int s = (int)ob[rowbase + xa], e = (int)ob[rowbase + xa + 1];
              if (s < e) proc8(s, e);
            }
          }
          int xb = cqx + k;
          if (xb < GD) {
            if ((rr++ & (LPQ - 1)) == g) {
              int s = (int)ob[rowbase + xb], e = (int)ob[rowbase + xb + 1];
              if (s < e) proc8(s, e);
            }
          }
        }
      }
    }
    // group reduce (hoisted shuffles — r19-proven): m = min over lanes of run[15]
    u64 m = run[15];
    {
      u64 o1 = shfl_xor_u64(m, 1);
      m = o1 < m ? o1 : m;
      u64 o2 = shfl_xor_u64(m, 2);
      m = o2 < m ? o2 : m;
      u64 o4 = shfl_xor_u64(m, 4);
      m = o4 < m ? o4 : m;
    }
    groupthr = m; // exact prune threshold for subsequent shells
    float d16 = __uint_as_float((u32)(m >> 32)); // NaN while no lane full -> no stop
    float kw = (float)k * CW;
    if (d16 < kw * kw * 0.9999f) break;
  }

  // 3-stage shuffle merge (shuffles hoisted into oth[] -> safe): after each
  // stage all lanes in the widening group hold the same sorted lowest-16.
#pragma unroll
  for (int st = 1; st <= 4; st <<= 1) {
    u64 oth[KNN];
#pragma unroll
    for (int i = 0; i < KNN; ++i) oth[i] = shfl_xor_u64(run[i], st);
#pragma unroll
    for (int i = 0; i < KNN; ++i) run[i] = MIN64(run[i], oth[KNN - 1 - i]);
#pragma unroll
    for (int jj = 8; jj >= 1; jj >>= 1) {
#pragma unroll
      for (int ii = 0; ii < KNN; ++ii) {
        if ((ii & jj) == 0) { SWAP64(run[ii], run[ii | jj]) }
      }
    }
  }

  if (g != 0) return;

  // ---- features (r17-proven epilogue) ----
  float nx[KNN], ny[KNN], nz[KNN];
  float sx = 0.f, sy = 0.f, sz = 0.f;
#pragma unroll
  for (int i = 0; i < KNN; ++i) {
    int ni = (int)(u32)run[i];
    float4 c4 = pts4[bbase + ni];
    nx[i] = c4.x; ny[i] = c4.y; nz[i] = c4.z;
    sx += c4.x; sy += c4.y; sz += c4.z;
  }
  const float invK = 1.0f / 16.0f;
  float cx = sx * invK, cy = sy * invK, cz = sz * invK;

  float c00 = 0.f, c01 = 0.f, c02 = 0.f, c11 = 0.f, c12 = 0.f, c22 = 0.f;
#pragma unroll
  for (int i = 0; i < KNN; ++i) {
    float dx = nx[i] - cx, dy = ny[i] - cy, dz = nz[i] - cz;
    c00 += dx * dx; c01 += dx * dy; c02 += dx * dz;
    c11 += dy * dy; c12 += dy * dz; c22 += dz * dz;
  }
  const float inv15 = 1.0f / 15.0f;
  c00 *= inv15; c01 *= inv15; c02 *= inv15;
  c11 *= inv15; c12 *= inv15; c22 *= inv15;

  double a00 = c00, a01 = c01, a02 = c02, a11 = c11, a12 = c12, a22 = c22;
  double tr = a00 + a11 + a22;
  double qm = tr * (1.0 / 3.0);
  double p1 = a01 * a01 + a02 * a02 + a12 * a12;
  double b00 = a00 - qm, b11 = a11 - qm, b22 = a22 - qm;
  double p2 = b00 * b00 + b11 * b11 + b22 * b22 + 2.0 * p1;
  double lmin = qm;
  if (p2 > 0.0) {
    double p = sqrt(p2 * (1.0 / 6.0));
    double ip = 1.0 / p;
    double q00 = b00 * ip, q01 = a01 * ip, q02 = a02 * ip;
    double q11 = b11 * ip, q12 = a12 * ip, q22 = b22 * ip;
    double det = q00 * (q11 * q22 - q12 * q12) - q01 * (q01 * q22 - q12 * q02) +
                 q02 * (q01 * q12 - q11 * q02);
    double r = 0.5 * det;
    r = r < -1.0 ? -1.0 : (r > 1.0 ? 1.0 : r);
    double phi = acos(r) * (1.0 / 3.0);
    lmin = qm + 2.0 * p * cos(phi + 2.0943951023931953);
  }

  double m00 = a00 - lmin, m11 = a11 - lmin, m22 = a22 - lmin;
  double v0x = a01 * a12 - a02 * m11;
  double v0y = a02 * a01 - m00 * a12;
  double v0z = m00 * m11 - a01 * a01;
  double v1x = a01 * m22 - a02 * a12;
  double v1y = a02 * a02 - m00 * m22;
  double v1z = m00 * a12 - a01 * a02;
  double v2x = m11 * m22 - a12 * a12;
  double v2y = a12 * a02 - a01 * m22;
  double v2z = a01 * a12 - m11 * a02;
  double n0 = v0x * v0x + v0y * v0y + v0z * v0z;
  double n1 = v1x * v1x + v1y * v1y + v1z * v1z;
  double n2 = v2x * v2x + v2y * v2y + v2z * v2z;
  double vx, vy, vz, nn;
  if (n0 >= n1 && n0 >= n2) { vx = v0x; vy = v0y; vz = v0z; nn = n0; }
  else if (n1 >= n2)        { vx = v1x; vy = v1y; vz = v1z; nn = n1; }
  else                      { vx = v2x; vy = v2y; vz = v2z; nn = n2; }
  if (nn < 1e-60) { vx = 0.0; vy = 0.0; vz = 1.0; nn = 1.0; }
  double inn = 1.0 / sqrt(nn);
  float vxf = (float)(vx * inn), vyf = (float)(vy * inn), vzf = (float)(vz * inn);

  float s = 0.f;
#pragma unroll
  for (int i = 0; i < KNN; ++i) {
    s += fabsf((nx[i] - cx) * vxf + (ny[i] - cy) * vyf + (nz[i] - cz) * vzf);
  }

  int to = bbase + (int)qi;
  float nrx = normals[3 * (size_t)to + 0];
  float nry = normals[3 * (size_t)to + 1];
  float nrz = normals[3 * (size_t)to + 2];
  float dot = vxf * nrx + vyf * nry + vzf * nrz;
  float cons = fabsf(dot);
  float trf = c00 + c11 + c22;
  float curv = (float)lmin / fmaxf(trf, 1e-8f);
  float* o = out + (size_t)to * 6;
  o[0] = cons;
  o[1] = nrx;
  o[2] = nry;
  o[3] = nrz;
  o[4] = curv;
  o[5] = s * invK;
}

extern "C" void kernel_launch(void* const* d_in, const int* in_sizes, int n_in,
                              void* d_out, int out_size, void* d_ws, size_t ws_size,
                              hipStream_t stream) {
  const float* xyz = (const float*)d_in[0];
  const float* normals = (const float*)d_in[1];
  float* out = (float*)d_out;

  float4* pts4 = (float4*)d_ws;            // NQ
  float4* spts = pts4 + NQ;                // NQ (cell-sorted, w=(float)idx)
  u32* cnt = (u32*)(spts + NQ);            // 2*GD3
  u32* cur = cnt + 2 * GD3;                // 2*GD3
  u32* off = cur + 2 * GD3;                // 2*OFFST
  u32* cellid = off + 2 * OFFST;           // NQ

  zero_kernel<<<(2 * GD3) / 256, 256, 0, stream>>>(cnt);
  pack_kernel<<<NQ / 256, 256, 0, stream>>>(xyz, pts4, cellid, cnt);
  scan_kernel<<<2, 1024, 0, stream>>>(cnt, off, cur);
  scatter_kernel<<<NQ / 256, 256, 0, stream>>>(pts4, cellid, cur, spts);
  query_kernel<<<NQ / (64 / LPQ), 64, 0, stream>>>(pts4, spts, off, normals, out);
}

// Round 21
// 130.894 us; speedup vs baseline: 8.9600x; 8.4374x over previous
//
#include <hip/hip_runtime.h>

// HybridGeometryFeatures: B=2, N=12288, K=16 NN (excl self) + covariance eig features.
// REVERT to r15 (proven 131.1us, absmax 0.0039) per the pre-committed decision
// rule after the grid detour (r16-r20) failed to beat it:
//   r17 thread-per-query grid: correct but latency-starved (384 waves, 699us)
//   r19/r20 8-lane grid: correct but wave-divergence amplified busy-work ~8x.
// knn: RQ=2 queries/thread, LDS-staged chunks of 768, branchless top-8 of
//      quantized keys key=(bits(s)&0xFFFFFC00)|relidx, s=(|q|^2+|p|^2)-2q.p.
//      Converged at 108-112us across 6 structurally distinct staging designs
//      (~77% of the practically-achievable VALU issue rate for all-pairs).
// feat: one THREAD per query, AoS float4 gathers, exact f32 d2 recompute,
//       u64 (d2bits<<32|idx) keys, Batcher sort-8 + bitonic pad-merge into
//       sorted-16 run; centroid/cov + f64 eigensolve + features.
// ws: xs/ys/zs/ps (393KB) | pts4 AoS (393KB) | cidx u16 [NQ][128] (6.3MB).

#define NPTS 12288
#define NBATCH 2
#define NQ (NPTS * NBATCH)
#define KNN 16
#define NCH 16
#define CHSZ (NPTS / NCH) // 768
#define MKEEP 8
#define RQ 2
#define QGRP (256 * RQ)   // 512 queries per block
#define NQB (NQ / QGRP)   // 48

typedef unsigned long long u64;
typedef unsigned short u16;
typedef unsigned int u32;

#define SWAPU(a, b) { u32 _lo = min(a, b); u32 _hi = max(a, b); a = _lo; b = _hi; }
#define SWAP64(a, b) { u64 _lo = (a) < (b) ? (a) : (b); u64 _hi = (a) < (b) ? (b) : (a); a = _lo; b = _hi; }
#define MIN64(a, b) ((a) < (b) ? (a) : (b))
#define DIST(dst, px, py, pz) { float _dx = Qx - (px); float _dy = Qy - (py); float _dz = Qz - (pz); \
                                dst = fmaf(_dz, _dz, fmaf(_dy, _dy, _dx * _dx)); }
#define KEY(kk, dd, rel) { kk = (__float_as_uint(dd) & 0xFFFFFC00u) | (u32)(rel); }

__global__ __launch_bounds__(256) void pack_kernel(const float* __restrict__ xyz,
                                                   float* __restrict__ xs,
                                                   float* __restrict__ ys,
                                                   float* __restrict__ zs,
                                                   float* __restrict__ ps,
                                                   float4* __restrict__ pts4) {
  int i = blockIdx.x * 256 + threadIdx.x;
  if (i < NQ) {
    float x = xyz[3 * i + 0], y = xyz[3 * i + 1], z = xyz[3 * i + 2];
    float pp = fmaf(z, z, fmaf(y, y, x * x));
    xs[i] = x; ys[i] = y; zs[i] = z;
    ps[i] = pp;
    pts4[i] = make_float4(x, y, z, pp);
  }
}

// One thread = RQ queries x one chunk of 768. LDS-staged candidates; the 8
// ds_read_b128/batch are amortized over RQ independent sort networks.
__global__ __launch_bounds__(256) void knn_kernel(const float* __restrict__ xs,
                                                  const float* __restrict__ ys,
                                                  const float* __restrict__ zs,
                                                  const float* __restrict__ ps,
                                                  u16* __restrict__ cidx) {
  int bid = blockIdx.x;
  int qb = bid % NQB;
  int chk = bid / NQB;
  int qbase = qb * QGRP;               // uniform; 12288 % 512 == 0 -> b uniform
  int b = qbase / NPTS;
  int base = b * NPTS + chk * CHSZ;

  __shared__ __align__(16) float lx[CHSZ];
  __shared__ __align__(16) float ly[CHSZ];
  __shared__ __align__(16) float lz[CHSZ];
  __shared__ __align__(16) float lp[CHSZ];
  {
    float4* sx = (float4*)lx; float4* sy = (float4*)ly;
    float4* sz = (float4*)lz; float4* sp = (float4*)lp;
    const float4* gx = (const float4*)(xs + base);
    const float4* gy = (const float4*)(ys + base);
    const float4* gz = (const float4*)(zs + base);
    const float4* gp = (const float4*)(ps + base);
    if (threadIdx.x < CHSZ / 4) {
      sx[threadIdx.x] = gx[threadIdx.x];
      sy[threadIdx.x] = gy[threadIdx.x];
      sz[threadIdx.x] = gz[threadIdx.x];
      sp[threadIdx.x] = gp[threadIdx.x];
    }
  }
  __syncthreads();

  // per-thread query pair (stride 256 -> coalesced loads)
  float m2x[RQ], m2y[RQ], m2z[RQ], qq[RQ];
#pragma unroll
  for (int k = 0; k < RQ; ++k) {
    int q = qbase + k * 256 + threadIdx.x;
    m2x[k] = -2.0f * xs[q];
    m2y[k] = -2.0f * ys[q];
    m2z[k] = -2.0f * zs[q];
    qq[k] = ps[q];
  }

  u32 run[RQ][8];
#pragma unroll
  for (int k = 0; k < RQ; ++k)
#pragma unroll
    for (int j = 0; j < 8; ++j) run[k][j] = ~0u;

  const float4* lx4 = (const float4*)lx;
  const float4* ly4 = (const float4*)ly;
  const float4* lz4 = (const float4*)lz;
  const float4* lp4 = (const float4*)lp;

#pragma unroll 1
  for (int c0 = 0; c0 < CHSZ; c0 += 8) {
    int i4 = c0 >> 2;
    // 8 LDS vector reads per batch, shared by both queries
    float4 xA = lx4[i4], xB = lx4[i4 + 1];
    float4 yA = ly4[i4], yB = ly4[i4 + 1];
    float4 zA = lz4[i4], zB = lz4[i4 + 1];
    float4 pA = lp4[i4], pB = lp4[i4 + 1];

#pragma unroll
    for (int k = 0; k < RQ; ++k) {
      float M2X = m2x[k], M2Y = m2y[k], M2Z = m2z[k], QQ = qq[k];
#define SVAL(dst, px, py, pz, pp) dst = fmaf(M2X, (px), fmaf(M2Y, (py), fmaf(M2Z, (pz), QQ + (pp))));
      float e0, e1, e2, e3, e4, e5, e6, e7;
      SVAL(e0, xA.x, yA.x, zA.x, pA.x) SVAL(e1, xA.y, yA.y, zA.y, pA.y)
      SVAL(e2, xA.z, yA.z, zA.z, pA.z) SVAL(e3, xA.w, yA.w, zA.w, pA.w)
      SVAL(e4, xB.x, yB.x, zB.x, pB.x) SVAL(e5, xB.y, yB.y, zB.y, pB.y)
      SVAL(e6, xB.z, yB.z, zB.z, pB.z) SVAL(e7, xB.w, yB.w, zB.w, pB.w)
#undef SVAL
      u32 d0, d1, d2, d3, d4, d5, d6, d7;
      KEY(d0, e0, c0 + 0); KEY(d1, e1, c0 + 1); KEY(d2, e2, c0 + 2); KEY(d3, e3, c0 + 3);
      KEY(d4, e4, c0 + 4); KEY(d5, e5, c0 + 5); KEY(d6, e6, c0 + 6); KEY(d7, e7, c0 + 7);
      // Batcher sort-8 ascending (19 CEs)
      SWAPU(d0, d1) SWAPU(d2, d3) SWAPU(d4, d5) SWAPU(d6, d7)
      SWAPU(d0, d2) SWAPU(d1, d3) SWAPU(d4, d6) SWAPU(d5, d7)
      SWAPU(d1, d2) SWAPU(d5, d6)
      SWAPU(d0, d4) SWAPU(d1, d5) SWAPU(d2, d6) SWAPU(d3, d7)
      SWAPU(d2, d4) SWAPU(d3, d5)
      SWAPU(d1, d2) SWAPU(d3, d4) SWAPU(d5, d6)
      // keep lowest-8 of (run, batch): cross-min -> bitonic resort (12 CEs)
      u32 m0 = min(run[k][0], d7), m1 = min(run[k][1], d6);
      u32 m2 = min(run[k][2], d5), m3 = min(run[k][3], d4);
      u32 m4 = min(run[k][4], d3), m5 = min(run[k][5], d2);
      u32 m6 = min(run[k][6], d1), m7 = min(run[k][7], d0);
      SWAPU(m0, m4) SWAPU(m1, m5) SWAPU(m2, m6) SWAPU(m3, m7)
      SWAPU(m0, m2) SWAPU(m1, m3) SWAPU(m4, m6) SWAPU(m5, m7)
      SWAPU(m0, m1) SWAPU(m2, m3) SWAPU(m4, m5) SWAPU(m6, m7)
      run[k][0] = m0; run[k][1] = m1; run[k][2] = m2; run[k][3] = m3;
      run[k][4] = m4; run[k][5] = m5; run[k][6] = m6; run[k][7] = m7;
    }
  }

  // epilogue: per query, strip to global-in-batch indices, 16B store
  u32 cb = (u32)(chk * CHSZ);
#pragma unroll
  for (int k = 0; k < RQ; ++k) {
    int q = qbase + k * 256 + threadIdx.x;
    uint4 w;
    w.x = (cb + (run[k][0] & 1023u)) | ((cb + (run[k][1] & 1023u)) << 16);
    w.y = (cb + (run[k][2] & 1023u)) | ((cb + (run[k][3] & 1023u)) << 16);
    w.z = (cb + (run[k][4] & 1023u)) | ((cb + (run[k][5] & 1023u)) << 16);
    w.w = (cb + (run[k][6] & 1023u)) | ((cb + (run[k][7] & 1023u)) << 16);
    *(uint4*)(cidx + (size_t)q * (NCH * MKEEP) + chk * MKEEP) = w;
  }
}

// One THREAD per query: exact u64 selection fully in registers, no shuffles.
// All point gathers via AoS float4 (1 scattered 16B load per candidate).
__global__ __launch_bounds__(64) void feat_kernel(const float4* __restrict__ pts4,
                                                  const float* __restrict__ normals,
                                                  const u16* __restrict__ cidx,
                                                  float* __restrict__ out) {
  int t = blockIdx.x * 64 + threadIdx.x; // query 0..NQ
  int b = t / NPTS;
  int qi = t - b * NPTS;
  int bbase = b * NPTS;

  float4 Qv = pts4[t];
  float Qx = Qv.x, Qy = Qv.y, Qz = Qv.z;

  const uint4* crow = (const uint4*)(cidx + (size_t)t * (NCH * MKEEP));

  u64 run[KNN];
#pragma unroll
  for (int i = 0; i < KNN; ++i) run[i] = ~0ULL;

#pragma unroll 1
  for (int ch = 0; ch < NCH; ++ch) {
    uint4 w = crow[ch]; // 8 u16 candidate indices
    int ix[8];
    ix[0] = (int)(w.x & 0xFFFFu); ix[1] = (int)(w.x >> 16);
    ix[2] = (int)(w.y & 0xFFFFu); ix[3] = (int)(w.y >> 16);
    ix[4] = (int)(w.z & 0xFFFFu); ix[5] = (int)(w.z >> 16);
    ix[6] = (int)(w.w & 0xFFFFu); ix[7] = (int)(w.w >> 16);
    u64 s0, s1, s2, s3, s4, s5, s6, s7;
#define MK(sv, j) { int _i = ix[j]; float4 _c = pts4[bbase + _i]; float _d; \
                    DIST(_d, _c.x, _c.y, _c.z); \
                    sv = ((u64)__float_as_uint(_d) << 32) | (u32)_i; if (_i == qi) sv = ~0ULL; }
    MK(s0, 0) MK(s1, 1) MK(s2, 2) MK(s3, 3) MK(s4, 4) MK(s5, 5) MK(s6, 6) MK(s7, 7)
#undef MK
    // Batcher sort-8 ascending (19 CEs on u64)
    SWAP64(s0, s1) SWAP64(s2, s3) SWAP64(s4, s5) SWAP64(s6, s7)
    SWAP64(s0, s2) SWAP64(s1, s3) SWAP64(s4, s6) SWAP64(s5, s7)
    SWAP64(s1, s2) SWAP64(s5, s6)
    SWAP64(s0, s4) SWAP64(s1, s5) SWAP64(s2, s6) SWAP64(s3, s7)
    SWAP64(s2, s4) SWAP64(s3, s5)
    SWAP64(s1, s2) SWAP64(s3, s4) SWAP64(s5, s6)
    // pad-merge sorted-8 into sorted-16 run: halver (run asc, s asc padded INF)
    run[8]  = MIN64(run[8],  s7);
    run[9]  = MIN64(run[9],  s6);
    run[10] = MIN64(run[10], s5);
    run[11] = MIN64(run[11], s4);
    run[12] = MIN64(run[12], s3);
    run[13] = MIN64(run[13], s2);
    run[14] = MIN64(run[14], s1);
    run[15] = MIN64(run[15], s0);
    // run is now bitonic: bitonic-merge-16 ascending (4 stages x 8 CE)
#pragma unroll
    for (int j = 8; j >= 1; j >>= 1) {
#pragma unroll
      for (int i = 0; i < KNN; ++i) {
        if ((i & j) == 0) { SWAP64(run[i], run[i | j]) }
      }
    }
  }

  // gather the 16 selected neighbors (low words of run = indices)
  float nx[KNN], ny[KNN], nz[KNN];
  float sx = 0.f, sy = 0.f, sz = 0.f;
#pragma unroll
  for (int i = 0; i < KNN; ++i) {
    int ni = (int)(u32)run[i];
    float4 c4 = pts4[bbase + ni];
    nx[i] = c4.x; ny[i] = c4.y; nz[i] = c4.z;
    sx += c4.x; sy += c4.y; sz += c4.z;
  }
  const float invK = 1.0f / 16.0f;
  float cx = sx * invK, cy = sy * invK, cz = sz * invK;

  float c00 = 0.f, c01 = 0.f, c02 = 0.f, c11 = 0.f, c12 = 0.f, c22 = 0.f;
#pragma unroll
  for (int i = 0; i < KNN; ++i) {
    float dx = nx[i] - cx, dy = ny[i] - cy, dz = nz[i] - cz;
    c00 += dx * dx; c01 += dx * dy; c02 += dx * dz;
    c11 += dy * dy; c12 += dy * dz; c22 += dz * dz;
  }
  const float inv15 = 1.0f / 15.0f;
  c00 *= inv15; c01 *= inv15; c02 *= inv15;
  c11 *= inv15; c12 *= inv15; c22 *= inv15;

  // f64 analytic eigensolve (smallest eigenvalue) — proven path.
  double a00 = c00, a01 = c01, a02 = c02, a11 = c11, a12 = c12, a22 = c22;
  double tr = a00 + a11 + a22;
  double qm = tr * (1.0 / 3.0);
  double p1 = a01 * a01 + a02 * a02 + a12 * a12;
  double b00 = a00 - qm, b11 = a11 - qm, b22 = a22 - qm;
  double p2 = b00 * b00 + b11 * b11 + b22 * b22 + 2.0 * p1;
  double lmin = qm;
  if (p2 > 0.0) {
    double p = sqrt(p2 * (1.0 / 6.0));
    double ip = 1.0 / p;
    double q00 = b00 * ip, q01 = a01 * ip, q02 = a02 * ip;
    double q11 = b11 * ip, q12 = a12 * ip, q22 = b22 * ip;
    double det = q00 * (q11 * q22 - q12 * q12) - q01 * (q01 * q22 - q12 * q02) +
                 q02 * (q01 * q12 - q11 * q02);
    double r = 0.5 * det;
    r = r < -1.0 ? -1.0 : (r > 1.0 ? 1.0 : r);
    double phi = acos(r) * (1.0 / 3.0);
    lmin = qm + 2.0 * p * cos(phi + 2.0943951023931953);
  }

  // eigenvector: cross products of rows of (A - lmin I), pick largest.
  double m00 = a00 - lmin, m11 = a11 - lmin, m22 = a22 - lmin;
  double v0x = a01 * a12 - a02 * m11;
  double v0y = a02 * a01 - m00 * a12;
  double v0z = m00 * m11 - a01 * a01;
  double v1x = a01 * m22 - a02 * a12;
  double v1y = a02 * a02 - m00 * m22;
  double v1z = m00 * a12 - a01 * a02;
  double v2x = m11 * m22 - a12 * a12;
  double v2y = a12 * a02 - a01 * m22;
  double v2z = a01 * a12 - m11 * a02;
  double n0 = v0x * v0x + v0y * v0y + v0z * v0z;
  double n1 = v1x * v1x + v1y * v1y + v1z * v1z;
  double n2 = v2x * v2x + v2y * v2y + v2z * v2z;
  double vx, vy, vz, nn;
  if (n0 >= n1 && n0 >= n2) { vx = v0x; vy = v0y; vz = v0z; nn = n0; }
  else if (n1 >= n2)        { vx = v1x; vy = v1y; vz = v1z; nn = n1; }
  else                      { vx = v2x; vy = v2y; vz = v2z; nn = n2; }
  if (nn < 1e-60) { vx = 0.0; vy = 0.0; vz = 1.0; nn = 1.0; }
  double inn = 1.0 / sqrt(nn);
  float vxf = (float)(vx * inn), vyf = (float)(vy * inn), vzf = (float)(vz * inn);

  // roughness: mean |centered . v|
  float s = 0.f;
#pragma unroll
  for (int i = 0; i < KNN; ++i) {
    s += fabsf((nx[i] - cx) * vxf + (ny[i] - cy) * vyf + (nz[i] - cz) * vzf);
  }

  float nrx = normals[3 * (size_t)t + 0];
  float nry = normals[3 * (size_t)t + 1];
  float nrz = normals[3 * (size_t)t + 2];
  float dot = vxf * nrx + vyf * nry + vzf * nrz;
  float cons = fabsf(dot);
  float trf = c00 + c11 + c22;
  float curv = (float)lmin / fmaxf(trf, 1e-8f);
  float* o = out + (size_t)t * 6;
  o[0] = cons;
  o[1] = nrx;
  o[2] = nry;
  o[3] = nrz;
  o[4] = curv;
  o[5] = s * invK;
}

extern "C" void kernel_launch(void* const* d_in, const int* in_sizes, int n_in,
                              void* d_out, int out_size, void* d_ws, size_t ws_size,
                              hipStream_t stream) {
  const float* xyz = (const float*)d_in[0];
  const float* normals = (const float*)d_in[1];
  float* out = (float*)d_out;

  float* xs = (float*)d_ws;
  float* ys = xs + NQ;
  float* zs = ys + NQ;
  float* ps = zs + NQ;
  float4* pts4 = (float4*)(ps + NQ);   // NQ float4 (16B-aligned: offset 4*NQ floats)
  u16* cidx = (u16*)(pts4 + NQ);       // NQ*128 u16 = 6.3MB

  pack_kernel<<<NQ / 256, 256, 0, stream>>>(xyz, xs, ys, zs, ps, pts4);
  knn_kernel<<<NQB * NCH, 256, 0, stream>>>(xs, ys, zs, ps, cidx);
  feat_kernel<<<NQ / 64, 64, 0, stream>>>(pts4, normals, cidx, out);
}